// Round 3
// baseline (280.842 us; speedup 1.0000x reference)
//
#include <hip/hip_runtime.h>
#include <hip/hip_bf16.h>
#include <math.h>

// Problem constants
#define B_   8
#define H_   8
#define S_   2048
#define D_   64      // head dim
#define BH_  64      // B*H
#define DPROJ_ 512

typedef __attribute__((ext_vector_type(8)))  _Float16 f16x8;
typedef __attribute__((ext_vector_type(4)))  float    f32x4;
typedef __attribute__((ext_vector_type(16))) float    f32x16;
typedef __attribute__((ext_vector_type(4)))  int      i32x4;

static __device__ __forceinline__ short f16bits(float f) {
    return __builtin_bit_cast(short, (_Float16)f);   // v_cvt_f16_f32 (RNE)
}

static __device__ __forceinline__ f16x8 load8_f32_f16(const float* p) {
    const float4 a = ((const float4*)p)[0];
    const float4 b = ((const float4*)p)[1];
    f16x8 r;
    r[0] = (_Float16)a.x; r[1] = (_Float16)a.y; r[2] = (_Float16)a.z; r[3] = (_Float16)a.w;
    r[4] = (_Float16)b.x; r[5] = (_Float16)b.y; r[6] = (_Float16)b.z; r[7] = (_Float16)b.w;
    return r;
}

// exp2: guarantee a single v_exp_f32 (HW computes 2^x)
#if __has_builtin(__builtin_amdgcn_exp2f)
#define EXP2(x) __builtin_amdgcn_exp2f(x)
#else
#define EXP2(x) exp2f(x)
#endif

// permlane32_swap: newA = {A_lo, B_lo}, newB = {A_hi, B_hi}.
static __device__ __forceinline__ void pl32swap(unsigned int& a, unsigned int& b) {
#if __has_builtin(__builtin_amdgcn_permlane32_swap)
    auto r = __builtin_amdgcn_permlane32_swap((int)a, (int)b, false, false);
    a = (unsigned int)r[0];
    b = (unsigned int)r[1];
#else
    const bool lh0 = ((threadIdx.x & 63) < 32);
    unsigned int xa = (unsigned int)__shfl_xor((int)a, 32);
    unsigned int xb = (unsigned int)__shfl_xor((int)b, 32);
    unsigned int na = lh0 ? a : xb;
    unsigned int nb = lh0 ? xa : b;
    a = na; b = nb;
#endif
}

// ---------------------------------------------------------------------------
// Fused projection kernel (unchanged from round 2 — passed, minor cost).
//   kind 0=q, 1=k, 2=v.  q pre-scaled by 0.1125*log2(e) (exp2 softmax).
//   v_ws blocked [bh][s_tile][d][ks] so each 32-k V^T tile is contiguous 4KB.
// ---------------------------------------------------------------------------
#define QKST 520

__global__ __launch_bounds__(256)
void proj_kernel(const float* __restrict__ query, const float* __restrict__ key,
                 const float* __restrict__ value,
                 const float* __restrict__ Wq, const float* __restrict__ bq,
                 const float* __restrict__ Wk, const float* __restrict__ bk,
                 const float* __restrict__ Wv, const float* __restrict__ bv,
                 short* __restrict__ qws, short* __restrict__ kws,
                 short* __restrict__ vws)
{
    __shared__ __align__(16) short shbuf[16384];   // 32 KB, unioned per path

    const int tid  = threadIdx.x;
    const int wave = tid >> 6;
    const int lane = tid & 63;
    const int n    = lane & 15;
    const int quad = lane >> 4;
    const int kind = blockIdx.y;             // 0=q, 1=k, 2=v

    if (kind < 2) {
        short* tile = shbuf;                 // 16 x QKST = 16640 B
        const int r0   = blockIdx.x * 16;
        const int b    = r0 >> 11;
        const int s0   = r0 & 2047;
        // (1-dropout)/num_heads = 0.9/8 = 0.1125, times log2(e) for exp2 softmax
        const float QS = 0.16230319188537014f;

        const float* X    = kind ? key : query;
        const float* W    = kind ? Wk  : Wq;
        const float* bias = kind ? bk  : bq;
        short*       ows  = kind ? kws : qws;

        f16x8 af = load8_f32_f16(X + (r0 + n) * 32 + quad * 8);
        #pragma unroll
        for (int i = 0; i < 8; ++i) {
            const int c0 = wave * 128 + i * 16;
            f16x8 bfr = load8_f32_f16(W + (c0 + n) * 32 + quad * 8);
            f32x4 acc = {0.f, 0.f, 0.f, 0.f};
            acc = __builtin_amdgcn_mfma_f32_16x16x32_f16(af, bfr, acc, 0, 0, 0);
            const int c = c0 + n;
            const float bsf = bias[c];
            #pragma unroll
            for (int r = 0; r < 4; ++r) {
                float v = acc[r] + bsf;
                if (kind == 0) v *= QS;
                tile[(quad * 4 + r) * QKST + c] = f16bits(v);
            }
        }
        __syncthreads();

        #pragma unroll
        for (int k = 0; k < 4; ++k) {
            const int slot = k * 256 + tid;
            const int li   = slot & 7;
            const int chunk= slot >> 3;
            const int row  = chunk & 15;
            const int h    = chunk >> 4;
            uint4 vv = *(const uint4*)(tile + row * QKST + h * 64 + li * 8);
            *(uint4*)(ows + ((size_t)(b * 8 + h) * S_ + s0 + row) * 64 + li * 8) = vv;
        }
    } else {
        if (blockIdx.x >= 256) return;       // v path needs only 256 blocks
        short* vtile = shbuf;                // 2*256*32 shorts = 32768 B
        const int r0   = blockIdx.x * 64;
        const int b    = r0 >> 11;
        const int s0   = r0 & 2047;
        const int sub  = wave >> 1;
        const int sh   = (wave & 1) * 16;

        #pragma unroll
        for (int half = 0; half < 2; ++half) {
            const int cbh = half * 256;
            f16x8 bfr = load8_f32_f16(value + (r0 + sub * 32 + sh + n) * 32 + quad * 8);
            #pragma unroll
            for (int i = 0; i < 16; ++i) {
                const int c0 = cbh + i * 16;
                f16x8 af = load8_f32_f16(Wv + (c0 + n) * 32 + quad * 8);
                f32x4 acc = {0.f, 0.f, 0.f, 0.f};
                acc = __builtin_amdgcn_mfma_f32_16x16x32_f16(af, bfr, acc, 0, 0, 0);
                #pragma unroll
                for (int r = 0; r < 4; ++r) {
                    const int dc = c0 + quad * 4 + r;
                    float v = acc[r] + bv[dc];
                    vtile[(sub * 256 + (dc - cbh)) * 32 + sh + n] = f16bits(v);
                }
            }
            __syncthreads();

            #pragma unroll
            for (int k = 0; k < 8; ++k) {
                const int slot = k * 256 + tid;
                const int li   = slot & 3;
                const int cl   = (slot >> 2) & 255;
                const int sb   = slot >> 10;
                const int c    = cbh + cl;
                const int bh   = b * 8 + (c >> 6);
                const int d    = c & 63;
                const int stile= (s0 >> 5) + sb;
                uint4 vv = *(const uint4*)(vtile + (sb * 256 + cl) * 32 + li * 8);
                *(uint4*)(vws + (((size_t)bh * (S_ / 32) + stile) * 64 + d) * 32 + li * 8) = vv;
            }
            if (half == 0) __syncthreads();  // reuse vtile for second half
        }
    }
}

// ---------------------------------------------------------------------------
// Kernel 2: flash attention. R9: OCCUPANCY via block count (round-2 lesson:
// grid 512 blocks = 2 blocks/CU was the residency cap, not LDS/regs).
// Keep the proven 64-q-row wave body (round-1 showed 32-row waves double
// per-work VALU). Blocks shrink to 2 waves / 128 threads / 128 q-rows
// -> grid (BH, S/128) = 1024 blocks. LDS: K/V staging (19.4 KB) unioned
// with the epilogue transpose buffer (9.2 KB, reused after the final
// barrier) in ONE pool -> 19.5 KB/block; launch_bounds(128,3) -> no reg
// cap squeeze -> 3 waves/SIMD = 12 waves/CU (1.5x round 2).
// Staging: each thread moves 2x16B per tile (K chunks t,t+128; V same).
// T5 setprio(1) around MFMA clusters (waves now staggered across blocks,
// scheduler has role diversity to arbitrate).
// XCD grid (bh = blockIdx.x % 8 -> XCD) retained: FETCH 27 MB, L2-resident.
// ---------------------------------------------------------------------------
#define KST 72   // K lds row stride (shorts): 144B, 16B-aligned
#define VST 40   // V lds row stride (shorts): 80B, 16B-aligned
#define OTS 36   // epilogue LDS row stride (f32) for one 32-wide d-tile

#define KBUF_SH (2 * 32 * KST)          // 4608 shorts = 9216 B
#define VBUF_SH (2 * 64 * VST)          // 5120 shorts = 10240 B

__global__ __launch_bounds__(128, 3)
void flash_kernel(const short* __restrict__ qws, const short* __restrict__ kws,
                  const short* __restrict__ vws, float* __restrict__ out)
{
    // one pool: [K dbuf 9216 B][V dbuf 10240 B] = 19456 B; epilogue reuses
    // the front 9216 B (2 waves x 32x36 f32 = 9216 B) after the final barrier.
    __shared__ __align__(16) char pool[19456];
    short* ldsk = (short*)pool;
    short* ldsv = (short*)pool + KBUF_SH;

    const int tid  = threadIdx.x;        // 0..127
    const int wave = tid >> 6;           // 0..1
    const int lane = tid & 63;
    const int m32  = lane & 31;
    const int lh   = lane >> 5;          // lane-half
    const int koff = lh * 8;
    const int bh   = blockIdx.x;                     // XCD = bh % 8
    const int q0   = blockIdx.y * 128 + wave * 64;   // 64 q-rows per wave

    const short* qbase = qws + (size_t)bh * S_ * D_;
    const short* kbase = kws + (size_t)bh * S_ * D_;
    const short* vbase = vws + (size_t)bh * (S_ / 32) * 2048;  // blocked tiles

    // staging addresses: 256 16B-chunks per 4KB tile, 2 chunks/thread.
    // chunk c of K tile [32][64]: shorts [8c, 8c+8) = row c>>3, col (c&7)*8
    // chunk c of V tile [64][32]: shorts [8c, 8c+8) = row c>>2, col (c&3)*8
    short* kdst0 = ldsk + (tid >> 3) * KST + (tid & 7) * 8;
    short* kdst1 = kdst0 + 16 * KST;                 // chunk t+128 -> row+16
    short* vdst0 = ldsv + (tid >> 2) * VST + (tid & 3) * 8;
    short* vdst1 = vdst0 + 32 * VST;                 // chunk t+128 -> row+32

    // Q^T B-frags (held): qb[qg][h]: B[d=h*16+lh*8+j][q=m32]
    f16x8 qb[2][4];
    #pragma unroll
    for (int qg = 0; qg < 2; ++qg)
        #pragma unroll
        for (int h = 0; h < 4; ++h)
            qb[qg][h] = *(const f16x8*)(qbase + (q0 + qg * 32 + m32) * D_ + h * 16 + koff);

    f32x16 z16;
    #pragma unroll
    for (int r = 0; r < 16; ++r) z16[r] = 0.f;

    f32x16 o[2][2];      // [qg][d-tile] O^T accumulators
    float  pl[2] = {0.f, 0.f};
    #pragma unroll
    for (int qg = 0; qg < 2; ++qg)
        #pragma unroll
        for (int t = 0; t < 2; ++t)
            o[qg][t] = z16;

    // stage tile 0 into buffer 0 (2 x 16B per thread per tensor)
    {
        uint4 k0 = *(const uint4*)(kbase + (size_t)tid * 8);
        uint4 k1 = *(const uint4*)(kbase + (size_t)tid * 8 + 1024);
        uint4 v0 = *(const uint4*)(vbase + (size_t)tid * 8);
        uint4 v1 = *(const uint4*)(vbase + (size_t)tid * 8 + 1024);
        *(uint4*)kdst0 = k0;  *(uint4*)kdst1 = k1;
        *(uint4*)vdst0 = v0;  *(uint4*)vdst1 = v1;
    }
    __syncthreads();

    for (int it = 0; it < 64; ++it) {
        const int cur = it & 1, nx = cur ^ 1;

        // issue next-tile global loads early (coalesced 16B/thread chunks)
        uint4 k0, k1, v0, v1;
        if (it < 63) {
            const size_t tb = (size_t)(it + 1) * 2048 + tid * 8;
            k0 = *(const uint4*)(kbase + tb);
            k1 = *(const uint4*)(kbase + tb + 1024);
            v0 = *(const uint4*)(vbase + tb);
            v1 = *(const uint4*)(vbase + tb + 1024);
        }

        // ---- compute on buffer cur ----
        const short* kl = ldsk + cur * (32 * KST);
        const short* vl = ldsv + cur * (64 * VST);
        f16x8 kf[4], va[4];
        #pragma unroll
        for (int h = 0; h < 4; ++h)
            kf[h] = *(const f16x8*)(kl + m32 * KST + h * 16 + koff);
        #pragma unroll
        for (int t = 0; t < 2; ++t)
            #pragma unroll
            for (int kh = 0; kh < 2; ++kh)
                va[t * 2 + kh] = *(const f16x8*)(vl + (t * 32 + m32) * VST + kh * 16 + koff);

        #pragma unroll
        for (int qg = 0; qg < 2; ++qg) {
            __builtin_amdgcn_s_setprio(1);
            f32x16 st = __builtin_amdgcn_mfma_f32_32x32x16_f16(kf[0], qb[qg][0], z16, 0, 0, 0);
            #pragma unroll
            for (int h = 1; h < 4; ++h)
                st = __builtin_amdgcn_mfma_f32_32x32x16_f16(kf[h], qb[qg][h], st, 0, 0, 0);
            __builtin_amdgcn_s_setprio(0);

            float p[16];
            #pragma unroll
            for (int r = 0; r < 16; ++r) p[r] = EXP2(st[r]);
            float s01 = (p[0]+p[1]) + (p[2]+p[3]);
            float s23 = (p[4]+p[5]) + (p[6]+p[7]);
            float s45 = (p[8]+p[9]) + (p[10]+p[11]);
            float s67 = (p[12]+p[13]) + (p[14]+p[15]);
            pl[qg] += (s01 + s23) + (s45 + s67);

            unsigned int pk[8];
            #pragma unroll
            for (int i = 0; i < 8; ++i)
                pk[i] = __builtin_bit_cast(unsigned int,
                          __builtin_amdgcn_cvt_pkrtz(p[2 * i], p[2 * i + 1]));
            pl32swap(pk[0], pk[2]);
            pl32swap(pk[1], pk[3]);
            pl32swap(pk[4], pk[6]);
            pl32swap(pk[5], pk[7]);

            i32x4 bi0, bi1;
            bi0[0] = (int)pk[0]; bi0[1] = (int)pk[1];
            bi0[2] = (int)pk[2]; bi0[3] = (int)pk[3];
            bi1[0] = (int)pk[4]; bi1[1] = (int)pk[5];
            bi1[2] = (int)pk[6]; bi1[3] = (int)pk[7];
            f16x8 bf0 = __builtin_bit_cast(f16x8, bi0);
            f16x8 bf1 = __builtin_bit_cast(f16x8, bi1);

            __builtin_amdgcn_s_setprio(1);
            #pragma unroll
            for (int t = 0; t < 2; ++t) {
                o[qg][t] = __builtin_amdgcn_mfma_f32_32x32x16_f16(va[t * 2 + 0], bf0, o[qg][t], 0, 0, 0);
                o[qg][t] = __builtin_amdgcn_mfma_f32_32x32x16_f16(va[t * 2 + 1], bf1, o[qg][t], 0, 0, 0);
            }
            __builtin_amdgcn_s_setprio(0);
        }

        __syncthreads();   // all waves done reading buffer cur
        if (it < 63) {
            *(uint4*)(kdst0 + nx * (32 * KST)) = k0;
            *(uint4*)(kdst1 + nx * (32 * KST)) = k1;
            *(uint4*)(vdst0 + nx * (64 * VST)) = v0;
            *(uint4*)(vdst1 + nx * (64 * VST)) = v1;
        }
        __syncthreads();   // staging visible before next iter's reads
    }

    // epilogue: complete row sums across lane-halves, normalize, transpose
    // O^T -> O one 32-wide d-tile at a time through per-wave LDS (32x36 f32,
    // reusing the staging pool — all staging reads completed at final
    // barrier above), coalesced f32x4 stores.
    const int b = bh >> 3, h = bh & 7;
    float* ow = (float*)pool + wave * (32 * OTS);
    #pragma unroll
    for (int qg = 0; qg < 2; ++qg) {
        float rs = pl[qg] + __shfl_xor(pl[qg], 32);
        float rl = 1.0f / rs;
        #pragma unroll
        for (int t = 0; t < 2; ++t) {
            const f32x16& ot = o[qg][t];
            #pragma unroll
            for (int g = 0; g < 4; ++g) {
                f32x4 w;
                w[0] = ot[g * 4 + 0] * rl;
                w[1] = ot[g * 4 + 1] * rl;
                w[2] = ot[g * 4 + 2] * rl;
                w[3] = ot[g * 4 + 3] * rl;
                // element (q=m32, dcol=r+8g+4lh) of this 32-wide d-tile
                *(f32x4*)(ow + m32 * OTS + 8 * g + 4 * lh) = w;
            }
            #pragma unroll
            for (int c = 0; c < 4; ++c) {
                const int row = (lane >> 3) + 8 * c;       // q-row within 32-row group
                f32x4 v = *(const f32x4*)(ow + row * OTS + (lane & 7) * 4);
                const int sq = q0 + qg * 32 + row;
                *(f32x4*)(out + ((size_t)(b * S_ + sq)) * DPROJ_
                              + h * 64 + t * 32 + (lane & 7) * 4) = v;
            }
        }
    }
}

// ---------------------------------------------------------------------------
extern "C" void kernel_launch(void* const* d_in, const int* in_sizes, int n_in,
                              void* d_out, int out_size, void* d_ws, size_t ws_size,
                              hipStream_t stream)
{
    const float* query = (const float*)d_in[0];
    const float* key   = (const float*)d_in[1];
    const float* value = (const float*)d_in[2];
    // d_in[3] = mask (int32) -- only its shape feeds the reference; unused.
    const float* Wq = (const float*)d_in[4];
    const float* bq = (const float*)d_in[5];
    const float* Wk = (const float*)d_in[6];
    const float* bk = (const float*)d_in[7];
    const float* Wv = (const float*)d_in[8];
    const float* bv = (const float*)d_in[9];

    float* out = (float*)d_out;
    short* ws  = (short*)d_ws;
    const size_t TSZ = (size_t)BH_ * S_ * D_;
    short* qws = ws;
    short* kws = ws + TSZ;
    short* vws = ws + 2 * TSZ;

    proj_kernel<<<dim3((B_ * S_) / 16, 3), 256, 0, stream>>>(
        query, key, value, Wq, bq, Wk, bk, Wv, bv, qws, kws, vws);
    flash_kernel<<<dim3(BH_, S_ / 128), 128, 0, stream>>>(qws, kws, vws, out);
}

// Round 4
// 188.851 us; speedup vs baseline: 1.4871x; 1.4871x over previous
//
#include <hip/hip_runtime.h>
#include <hip/hip_bf16.h>
#include <math.h>

// Problem constants
#define B_   8
#define H_   8
#define S_   2048
#define D_   64      // head dim
#define BH_  64      // B*H
#define DPROJ_ 512

typedef __attribute__((ext_vector_type(8)))  _Float16 f16x8;
typedef __attribute__((ext_vector_type(4)))  float    f32x4;
typedef __attribute__((ext_vector_type(16))) float    f32x16;
typedef __attribute__((ext_vector_type(4)))  int      i32x4;

static __device__ __forceinline__ short f16bits(float f) {
    return __builtin_bit_cast(short, (_Float16)f);   // v_cvt_f16_f32 (RNE)
}

static __device__ __forceinline__ f16x8 load8_f32_f16(const float* p) {
    const float4 a = ((const float4*)p)[0];
    const float4 b = ((const float4*)p)[1];
    f16x8 r;
    r[0] = (_Float16)a.x; r[1] = (_Float16)a.y; r[2] = (_Float16)a.z; r[3] = (_Float16)a.w;
    r[4] = (_Float16)b.x; r[5] = (_Float16)b.y; r[6] = (_Float16)b.z; r[7] = (_Float16)b.w;
    return r;
}

// exp2: guarantee a single v_exp_f32 (HW computes 2^x)
#if __has_builtin(__builtin_amdgcn_exp2f)
#define EXP2(x) __builtin_amdgcn_exp2f(x)
#else
#define EXP2(x) exp2f(x)
#endif

// permlane32_swap: newA = {A_lo, B_lo}, newB = {A_hi, B_hi}.
static __device__ __forceinline__ void pl32swap(unsigned int& a, unsigned int& b) {
#if __has_builtin(__builtin_amdgcn_permlane32_swap)
    auto r = __builtin_amdgcn_permlane32_swap((int)a, (int)b, false, false);
    a = (unsigned int)r[0];
    b = (unsigned int)r[1];
#else
    const bool lh0 = ((threadIdx.x & 63) < 32);
    unsigned int xa = (unsigned int)__shfl_xor((int)a, 32);
    unsigned int xb = (unsigned int)__shfl_xor((int)b, 32);
    unsigned int na = lh0 ? a : xb;
    unsigned int nb = lh0 ? xa : b;
    a = na; b = nb;
#endif
}

// ---------------------------------------------------------------------------
// Fused projection kernel (unchanged — passed, minor cost).
//   kind 0=q, 1=k, 2=v.  q pre-scaled by 0.1125*log2(e) (exp2 softmax).
//   v_ws blocked [bh][s_tile][d][ks] so each 32-k V^T tile is contiguous 4KB.
// ---------------------------------------------------------------------------
#define QKST 520

__global__ __launch_bounds__(256)
void proj_kernel(const float* __restrict__ query, const float* __restrict__ key,
                 const float* __restrict__ value,
                 const float* __restrict__ Wq, const float* __restrict__ bq,
                 const float* __restrict__ Wk, const float* __restrict__ bk,
                 const float* __restrict__ Wv, const float* __restrict__ bv,
                 short* __restrict__ qws, short* __restrict__ kws,
                 short* __restrict__ vws)
{
    __shared__ __align__(16) short shbuf[16384];   // 32 KB, unioned per path

    const int tid  = threadIdx.x;
    const int wave = tid >> 6;
    const int lane = tid & 63;
    const int n    = lane & 15;
    const int quad = lane >> 4;
    const int kind = blockIdx.y;             // 0=q, 1=k, 2=v

    if (kind < 2) {
        short* tile = shbuf;                 // 16 x QKST = 16640 B
        const int r0   = blockIdx.x * 16;
        const int b    = r0 >> 11;
        const int s0   = r0 & 2047;
        // (1-dropout)/num_heads = 0.9/8 = 0.1125, times log2(e) for exp2 softmax
        const float QS = 0.16230319188537014f;

        const float* X    = kind ? key : query;
        const float* W    = kind ? Wk  : Wq;
        const float* bias = kind ? bk  : bq;
        short*       ows  = kind ? kws : qws;

        f16x8 af = load8_f32_f16(X + (r0 + n) * 32 + quad * 8);
        #pragma unroll
        for (int i = 0; i < 8; ++i) {
            const int c0 = wave * 128 + i * 16;
            f16x8 bfr = load8_f32_f16(W + (c0 + n) * 32 + quad * 8);
            f32x4 acc = {0.f, 0.f, 0.f, 0.f};
            acc = __builtin_amdgcn_mfma_f32_16x16x32_f16(af, bfr, acc, 0, 0, 0);
            const int c = c0 + n;
            const float bsf = bias[c];
            #pragma unroll
            for (int r = 0; r < 4; ++r) {
                float v = acc[r] + bsf;
                if (kind == 0) v *= QS;
                tile[(quad * 4 + r) * QKST + c] = f16bits(v);
            }
        }
        __syncthreads();

        #pragma unroll
        for (int k = 0; k < 4; ++k) {
            const int slot = k * 256 + tid;
            const int li   = slot & 7;
            const int chunk= slot >> 3;
            const int row  = chunk & 15;
            const int h    = chunk >> 4;
            uint4 vv = *(const uint4*)(tile + row * QKST + h * 64 + li * 8);
            *(uint4*)(ows + ((size_t)(b * 8 + h) * S_ + s0 + row) * 64 + li * 8) = vv;
        }
    } else {
        if (blockIdx.x >= 256) return;       // v path needs only 256 blocks
        short* vtile = shbuf;                // 2*256*32 shorts = 32768 B
        const int r0   = blockIdx.x * 64;
        const int b    = r0 >> 11;
        const int s0   = r0 & 2047;
        const int sub  = wave >> 1;
        const int sh   = (wave & 1) * 16;

        #pragma unroll
        for (int half = 0; half < 2; ++half) {
            const int cbh = half * 256;
            f16x8 bfr = load8_f32_f16(value + (r0 + sub * 32 + sh + n) * 32 + quad * 8);
            #pragma unroll
            for (int i = 0; i < 16; ++i) {
                const int c0 = cbh + i * 16;
                f16x8 af = load8_f32_f16(Wv + (c0 + n) * 32 + quad * 8);
                f32x4 acc = {0.f, 0.f, 0.f, 0.f};
                acc = __builtin_amdgcn_mfma_f32_16x16x32_f16(af, bfr, acc, 0, 0, 0);
                #pragma unroll
                for (int r = 0; r < 4; ++r) {
                    const int dc = c0 + quad * 4 + r;
                    float v = acc[r] + bv[dc];
                    vtile[(sub * 256 + (dc - cbh)) * 32 + sh + n] = f16bits(v);
                }
            }
            __syncthreads();

            #pragma unroll
            for (int k = 0; k < 8; ++k) {
                const int slot = k * 256 + tid;
                const int li   = slot & 3;
                const int cl   = (slot >> 2) & 255;
                const int sb   = slot >> 10;
                const int c    = cbh + cl;
                const int bh   = b * 8 + (c >> 6);
                const int d    = c & 63;
                const int stile= (s0 >> 5) + sb;
                uint4 vv = *(const uint4*)(vtile + (sb * 256 + cl) * 32 + li * 8);
                *(uint4*)(vws + (((size_t)bh * (S_ / 32) + stile) * 64 + d) * 32 + li * 8) = vv;
            }
            if (half == 0) __syncthreads();  // reuse vtile for second half
        }
    }
}

// ---------------------------------------------------------------------------
// Kernel 2: flash attention. R10 = exact round-2 structure (proven 82 us:
// 4 waves x 64 q-rows, 256-thr blocks, grid (BH, S/256)=512) with ONE change:
// SINGLE-BARRIER double-buffer loop.
// Round-3 lesson: occupancy cannot be bought by shrinking blocks — the
// 512-block grid caps residency at 2 blocks/CU, and more blocks degrade
// tile sharing (FETCH 27->35 MB, conflicts 2x, 82->192 us). Reverted.
// Single-barrier proof: iter it READS buf[cur], WRITES buf[nx] (other
// buffer). The only cross-iteration hazards are (reads of cur @ it) vs
// (writes of cur @ it+1) and (writes of nx @ it) vs (reads of nx @ it+1);
// both are separated by the ONE end-of-iteration barrier (lgkmcnt(0)
// drained by __syncthreads). The old first barrier was redundant — it cost
// 64 extra block-wide syncs + full vmcnt/lgkmcnt drains on the critical
// path (the ~20% barrier-drain stall class).
// Retained: XCD grid (bh=blockIdx.x, FETCH 27 MB L2-resident), exp2
// softmax (scale*log2e folded into Q), permlane32_swap packing.
// ---------------------------------------------------------------------------
#define KST 72   // K lds row stride (shorts): 144B, 16B-aligned
#define VST 40   // V lds row stride (shorts): 80B, 16B-aligned
#define OTS 36   // epilogue LDS row stride (f32) for one 32-wide d-tile

__global__ __launch_bounds__(256, 3)
void flash_kernel(const short* __restrict__ qws, const short* __restrict__ kws,
                  const short* __restrict__ vws, float* __restrict__ out)
{
    __shared__ __align__(16) short ldsk[2 * 32 * KST];   //  9216 B
    __shared__ __align__(16) short ldsv[2 * 64 * VST];   // 10240 B
    __shared__ __align__(16) float olds[4 * 32 * OTS];   // 18432 B (tot 37888)

    const int tid  = threadIdx.x;
    const int wave = tid >> 6;
    const int lane = tid & 63;
    const int m32  = lane & 31;
    const int lh   = lane >> 5;          // lane-half
    const int koff = lh * 8;
    const int bh   = blockIdx.x;                     // XCD = bh % 8
    const int q0   = blockIdx.y * 256 + wave * 64;   // 64 q-rows per wave

    const short* qbase = qws + (size_t)bh * S_ * D_;
    const short* kbase = kws + (size_t)bh * S_ * D_;
    const short* vbase = vws + (size_t)bh * (S_ / 32) * 2048;  // blocked tiles

    // staging addresses (per thread, fixed)
    short* kdst0 = ldsk + (tid >> 3) * KST + (tid & 7) * 8;   // K: 8 thr/row of 64
    short* vdst0 = ldsv + (tid >> 2) * VST + (tid & 3) * 8;   // V: 4 thr/row of 32

    // Q^T B-frags (held): qb[qg][h]: B[d=h*16+lh*8+j][q=m32]
    f16x8 qb[2][4];
    #pragma unroll
    for (int qg = 0; qg < 2; ++qg)
        #pragma unroll
        for (int h = 0; h < 4; ++h)
            qb[qg][h] = *(const f16x8*)(qbase + (q0 + qg * 32 + m32) * D_ + h * 16 + koff);

    f32x16 z16;
    #pragma unroll
    for (int r = 0; r < 16; ++r) z16[r] = 0.f;

    f32x16 o[2][2];      // [qg][d-tile] O^T accumulators
    float  pl[2] = {0.f, 0.f};
    #pragma unroll
    for (int qg = 0; qg < 2; ++qg)
        #pragma unroll
        for (int t = 0; t < 2; ++t)
            o[qg][t] = z16;

    // stage tile 0 into buffer 0
    {
        uint4 kr = *(const uint4*)(kbase + (size_t)tid * 8);
        uint4 vr = *(const uint4*)(vbase + (size_t)tid * 8);
        *(uint4*)kdst0 = kr;
        *(uint4*)vdst0 = vr;
    }
    __syncthreads();

    for (int it = 0; it < 64; ++it) {
        const int cur = it & 1, nx = cur ^ 1;

        // issue next-tile global loads early (coalesced 16B/thread, 4KB each);
        // latency hides under this iteration's compute.
        uint4 kr, vr;
        if (it < 63) {
            kr = *(const uint4*)(kbase + (size_t)(it + 1) * 2048 + tid * 8);
            vr = *(const uint4*)(vbase + (size_t)(it + 1) * 2048 + tid * 8);
        }

        // ---- compute on buffer cur ----
        const short* kl = ldsk + cur * (32 * KST);
        const short* vl = ldsv + cur * (64 * VST);
        f16x8 kf[4], va[4];
        #pragma unroll
        for (int h = 0; h < 4; ++h)
            kf[h] = *(const f16x8*)(kl + m32 * KST + h * 16 + koff);
        #pragma unroll
        for (int t = 0; t < 2; ++t)
            #pragma unroll
            for (int kh = 0; kh < 2; ++kh)
                va[t * 2 + kh] = *(const f16x8*)(vl + (t * 32 + m32) * VST + kh * 16 + koff);

        #pragma unroll
        for (int qg = 0; qg < 2; ++qg) {
            f32x16 st = __builtin_amdgcn_mfma_f32_32x32x16_f16(kf[0], qb[qg][0], z16, 0, 0, 0);
            #pragma unroll
            for (int h = 1; h < 4; ++h)
                st = __builtin_amdgcn_mfma_f32_32x32x16_f16(kf[h], qb[qg][h], st, 0, 0, 0);

            float p[16];
            #pragma unroll
            for (int r = 0; r < 16; ++r) p[r] = EXP2(st[r]);
            float s01 = (p[0]+p[1]) + (p[2]+p[3]);
            float s23 = (p[4]+p[5]) + (p[6]+p[7]);
            float s45 = (p[8]+p[9]) + (p[10]+p[11]);
            float s67 = (p[12]+p[13]) + (p[14]+p[15]);
            pl[qg] += (s01 + s23) + (s45 + s67);

            unsigned int pk[8];
            #pragma unroll
            for (int i = 0; i < 8; ++i)
                pk[i] = __builtin_bit_cast(unsigned int,
                          __builtin_amdgcn_cvt_pkrtz(p[2 * i], p[2 * i + 1]));
            // pair swaps: after these, bi0 = {pk0,pk1,pk2,pk3}, bi1 = {pk4..pk7}
            pl32swap(pk[0], pk[2]);
            pl32swap(pk[1], pk[3]);
            pl32swap(pk[4], pk[6]);
            pl32swap(pk[5], pk[7]);

            i32x4 bi0, bi1;
            bi0[0] = (int)pk[0]; bi0[1] = (int)pk[1];
            bi0[2] = (int)pk[2]; bi0[3] = (int)pk[3];
            bi1[0] = (int)pk[4]; bi1[1] = (int)pk[5];
            bi1[2] = (int)pk[6]; bi1[3] = (int)pk[7];
            f16x8 bf0 = __builtin_bit_cast(f16x8, bi0);
            f16x8 bf1 = __builtin_bit_cast(f16x8, bi1);

            #pragma unroll
            for (int t = 0; t < 2; ++t) {
                o[qg][t] = __builtin_amdgcn_mfma_f32_32x32x16_f16(va[t * 2 + 0], bf0, o[qg][t], 0, 0, 0);
                o[qg][t] = __builtin_amdgcn_mfma_f32_32x32x16_f16(va[t * 2 + 1], bf1, o[qg][t], 0, 0, 0);
            }
        }

        // stage into the OTHER buffer (no barrier needed before: concurrent
        // readers are on buf[cur], writers on buf[nx]).
        if (it < 63) {
            *(uint4*)(kdst0 + nx * (32 * KST)) = kr;
            *(uint4*)(vdst0 + nx * (64 * VST)) = vr;
        }
        __syncthreads();   // single barrier: orders it's reads/writes vs it+1
    }

    // epilogue: complete row sums across lane-halves, normalize, transpose
    // O^T -> O one 32-wide d-tile at a time through per-wave LDS (32x36 f32),
    // coalesced f32x4 stores (128B per 8 lanes).
    const int b = bh >> 3, h = bh & 7;
    float* ow = olds + wave * (32 * OTS);
    #pragma unroll
    for (int qg = 0; qg < 2; ++qg) {
        float rs = pl[qg] + __shfl_xor(pl[qg], 32);
        float rl = 1.0f / rs;
        #pragma unroll
        for (int t = 0; t < 2; ++t) {
            const f32x16& ot = o[qg][t];
            #pragma unroll
            for (int g = 0; g < 4; ++g) {
                f32x4 w;
                w[0] = ot[g * 4 + 0] * rl;
                w[1] = ot[g * 4 + 1] * rl;
                w[2] = ot[g * 4 + 2] * rl;
                w[3] = ot[g * 4 + 3] * rl;
                // element (q=m32, dcol=r+8g+4lh) of this 32-wide d-tile
                *(f32x4*)(ow + m32 * OTS + 8 * g + 4 * lh) = w;
            }
            #pragma unroll
            for (int c = 0; c < 4; ++c) {
                const int row = (lane >> 3) + 8 * c;       // q-row within 32-row group
                f32x4 v = *(const f32x4*)(ow + row * OTS + (lane & 7) * 4);
                const int sq = q0 + qg * 32 + row;
                *(f32x4*)(out + ((size_t)(b * S_ + sq)) * DPROJ_
                              + h * 64 + t * 32 + (lane & 7) * 4) = v;
            }
        }
    }
}

// ---------------------------------------------------------------------------
extern "C" void kernel_launch(void* const* d_in, const int* in_sizes, int n_in,
                              void* d_out, int out_size, void* d_ws, size_t ws_size,
                              hipStream_t stream)
{
    const float* query = (const float*)d_in[0];
    const float* key   = (const float*)d_in[1];
    const float* value = (const float*)d_in[2];
    // d_in[3] = mask (int32) -- only its shape feeds the reference; unused.
    const float* Wq = (const float*)d_in[4];
    const float* bq = (const float*)d_in[5];
    const float* Wk = (const float*)d_in[6];
    const float* bk = (const float*)d_in[7];
    const float* Wv = (const float*)d_in[8];
    const float* bv = (const float*)d_in[9];

    float* out = (float*)d_out;
    short* ws  = (short*)d_ws;
    const size_t TSZ = (size_t)BH_ * S_ * D_;
    short* qws = ws;
    short* kws = ws + TSZ;
    short* vws = ws + 2 * TSZ;

    proj_kernel<<<dim3((B_ * S_) / 16, 3), 256, 0, stream>>>(
        query, key, value, Wq, bq, Wk, bk, Wv, bv, qws, kws, vws);
    flash_kernel<<<dim3(BH_, S_ / 256), 256, 0, stream>>>(qws, kws, vws, out);
}

// Round 5
// 185.011 us; speedup vs baseline: 1.5180x; 1.0208x over previous
//
#include <hip/hip_runtime.h>
#include <hip/hip_bf16.h>
#include <math.h>

// Problem constants
#define B_   8
#define H_   8
#define S_   2048
#define D_   64      // head dim
#define BH_  64      // B*H
#define DPROJ_ 512

typedef __attribute__((ext_vector_type(8)))  _Float16 f16x8;
typedef __attribute__((ext_vector_type(4)))  float    f32x4;
typedef __attribute__((ext_vector_type(16))) float    f32x16;
typedef __attribute__((ext_vector_type(4)))  int      i32x4;

static __device__ __forceinline__ short f16bits(float f) {
    return __builtin_bit_cast(short, (_Float16)f);   // v_cvt_f16_f32 (RNE)
}

static __device__ __forceinline__ f16x8 load8_f32_f16(const float* p) {
    const float4 a = ((const float4*)p)[0];
    const float4 b = ((const float4*)p)[1];
    f16x8 r;
    r[0] = (_Float16)a.x; r[1] = (_Float16)a.y; r[2] = (_Float16)a.z; r[3] = (_Float16)a.w;
    r[4] = (_Float16)b.x; r[5] = (_Float16)b.y; r[6] = (_Float16)b.z; r[7] = (_Float16)b.w;
    return r;
}

// exp2: guarantee a single v_exp_f32 (HW computes 2^x)
#if __has_builtin(__builtin_amdgcn_exp2f)
#define EXP2(x) __builtin_amdgcn_exp2f(x)
#else
#define EXP2(x) exp2f(x)
#endif

// permlane32_swap: newA = {A_lo, B_lo}, newB = {A_hi, B_hi}.
static __device__ __forceinline__ void pl32swap(unsigned int& a, unsigned int& b) {
#if __has_builtin(__builtin_amdgcn_permlane32_swap)
    auto r = __builtin_amdgcn_permlane32_swap((int)a, (int)b, false, false);
    a = (unsigned int)r[0];
    b = (unsigned int)r[1];
#else
    const bool lh0 = ((threadIdx.x & 63) < 32);
    unsigned int xa = (unsigned int)__shfl_xor((int)a, 32);
    unsigned int xb = (unsigned int)__shfl_xor((int)b, 32);
    unsigned int na = lh0 ? a : xb;
    unsigned int nb = lh0 ? xa : b;
    a = na; b = nb;
#endif
}

// ---------------------------------------------------------------------------
// Fused projection kernel (unchanged — passed, minor cost).
//   kind 0=q, 1=k, 2=v.  q pre-scaled by 0.1125*log2(e) (exp2 softmax).
//   v_ws blocked [bh][s_tile][d][ks] so each 32-k V^T tile is contiguous 4KB.
// ---------------------------------------------------------------------------
#define QKST 520

__global__ __launch_bounds__(256)
void proj_kernel(const float* __restrict__ query, const float* __restrict__ key,
                 const float* __restrict__ value,
                 const float* __restrict__ Wq, const float* __restrict__ bq,
                 const float* __restrict__ Wk, const float* __restrict__ bk,
                 const float* __restrict__ Wv, const float* __restrict__ bv,
                 short* __restrict__ qws, short* __restrict__ kws,
                 short* __restrict__ vws)
{
    __shared__ __align__(16) short shbuf[16384];   // 32 KB, unioned per path

    const int tid  = threadIdx.x;
    const int wave = tid >> 6;
    const int lane = tid & 63;
    const int n    = lane & 15;
    const int quad = lane >> 4;
    const int kind = blockIdx.y;             // 0=q, 1=k, 2=v

    if (kind < 2) {
        short* tile = shbuf;                 // 16 x QKST = 16640 B
        const int r0   = blockIdx.x * 16;
        const int b    = r0 >> 11;
        const int s0   = r0 & 2047;
        // (1-dropout)/num_heads = 0.9/8 = 0.1125, times log2(e) for exp2 softmax
        const float QS = 0.16230319188537014f;

        const float* X    = kind ? key : query;
        const float* W    = kind ? Wk  : Wq;
        const float* bias = kind ? bk  : bq;
        short*       ows  = kind ? kws : qws;

        f16x8 af = load8_f32_f16(X + (r0 + n) * 32 + quad * 8);
        #pragma unroll
        for (int i = 0; i < 8; ++i) {
            const int c0 = wave * 128 + i * 16;
            f16x8 bfr = load8_f32_f16(W + (c0 + n) * 32 + quad * 8);
            f32x4 acc = {0.f, 0.f, 0.f, 0.f};
            acc = __builtin_amdgcn_mfma_f32_16x16x32_f16(af, bfr, acc, 0, 0, 0);
            const int c = c0 + n;
            const float bsf = bias[c];
            #pragma unroll
            for (int r = 0; r < 4; ++r) {
                float v = acc[r] + bsf;
                if (kind == 0) v *= QS;
                tile[(quad * 4 + r) * QKST + c] = f16bits(v);
            }
        }
        __syncthreads();

        #pragma unroll
        for (int k = 0; k < 4; ++k) {
            const int slot = k * 256 + tid;
            const int li   = slot & 7;
            const int chunk= slot >> 3;
            const int row  = chunk & 15;
            const int h    = chunk >> 4;
            uint4 vv = *(const uint4*)(tile + row * QKST + h * 64 + li * 8);
            *(uint4*)(ows + ((size_t)(b * 8 + h) * S_ + s0 + row) * 64 + li * 8) = vv;
        }
    } else {
        if (blockIdx.x >= 256) return;       // v path needs only 256 blocks
        short* vtile = shbuf;                // 2*256*32 shorts = 32768 B
        const int r0   = blockIdx.x * 64;
        const int b    = r0 >> 11;
        const int s0   = r0 & 2047;
        const int sub  = wave >> 1;
        const int sh   = (wave & 1) * 16;

        #pragma unroll
        for (int half = 0; half < 2; ++half) {
            const int cbh = half * 256;
            f16x8 bfr = load8_f32_f16(value + (r0 + sub * 32 + sh + n) * 32 + quad * 8);
            #pragma unroll
            for (int i = 0; i < 16; ++i) {
                const int c0 = cbh + i * 16;
                f16x8 af = load8_f32_f16(Wv + (c0 + n) * 32 + quad * 8);
                f32x4 acc = {0.f, 0.f, 0.f, 0.f};
                acc = __builtin_amdgcn_mfma_f32_16x16x32_f16(af, bfr, acc, 0, 0, 0);
                #pragma unroll
                for (int r = 0; r < 4; ++r) {
                    const int dc = c0 + quad * 4 + r;
                    float v = acc[r] + bv[dc];
                    vtile[(sub * 256 + (dc - cbh)) * 32 + sh + n] = f16bits(v);
                }
            }
            __syncthreads();

            #pragma unroll
            for (int k = 0; k < 8; ++k) {
                const int slot = k * 256 + tid;
                const int li   = slot & 3;
                const int cl   = (slot >> 2) & 255;
                const int sb   = slot >> 10;
                const int c    = cbh + cl;
                const int bh   = b * 8 + (c >> 6);
                const int d    = c & 63;
                const int stile= (s0 >> 5) + sb;
                uint4 vv = *(const uint4*)(vtile + (sb * 256 + cl) * 32 + li * 8);
                *(uint4*)(vws + (((size_t)bh * (S_ / 32) + stile) * 64 + d) * 32 + li * 8) = vv;
            }
            if (half == 0) __syncthreads();  // reuse vtile for second half
        }
    }
}

// ---------------------------------------------------------------------------
// Kernel 2: flash attention. R11: PIPELINE DEPTH 2.
// Round-4 lesson: removing a barrier was ~1% — barrier count is not the
// stall. The stall: per wave-iter, the exposed chain head after each
// barrier (ds_read 8 frags -> lgkm wait -> QK) serializes iterations; with
// 2 waves/SIMD (grid-limited) nothing covers it. Double-buffering gives
// ZERO cross-iteration ILP because next tile's frags live in the buffer
// being written this iteration.
// Fix: TRIPLE-buffer LDS + register fragment prefetch (ping-pong A/B sets,
// loop unrolled x2, no copies). At iter it the wave already holds tile
// it's fragments in regs: MFMAs issue immediately post-barrier with zero
// memory wait. Overlapped under compute: global loads (tile it+2) and
// ds_reads of tile it+1 frags from the 3rd buffer; ds_write(it+2) lands
// before the single barrier.
// Hazards (buffer b=(it+2)%3 written at it; previous readers were frag
// loads at it-2, two barriers earlier): safe.
// launch_bounds(256,2): +64 VGPR for 2nd frag set; residency is
// grid-limited to 2 blocks/CU regardless.
// Retained: 4 waves x 64 q-rows, grid (BH, S/256), exp2 softmax,
// permlane32_swap packing, issue-early/write-late staging.
// ---------------------------------------------------------------------------
#define KST 72   // K lds row stride (shorts): 144B, 16B-aligned
#define VST 40   // V lds row stride (shorts): 80B, 16B-aligned
#define OTS 36   // epilogue LDS row stride (f32) for one 32-wide d-tile

static __device__ __forceinline__ void flash_step(
    int it,
    const short* __restrict__ kbase, const short* __restrict__ vbase,
    const short* ldsk, const short* ldsv,
    short* kdst0, short* vdst0,
    int m32, int koff, int tid,
    int& rOff, int& wOff, int& fOff,
    f16x8 (&kfc)[4], f16x8 (&vac)[4],          // current tile frags (in regs)
    f16x8 (&kfn)[4], f16x8 (&van)[4],          // next tile frags (filled here)
    const f16x8 (&qb)[2][4], const f32x16& z16,
    f32x16 (&o)[2][2], float (&pl)[2])
{
    const bool doStage = (it < 62);            // tile it+2 exists
    const bool doNext  = (it < 63);            // tile it+1 exists

    // (a) issue global loads for tile it+2 (latency hides under compute)
    uint4 kr, vr;
    if (doStage) {
        const size_t tb = (size_t)(it + 2) * 2048 + tid * 8;
        kr = *(const uint4*)(kbase + tb);
        vr = *(const uint4*)(vbase + tb);
    }

    // (b) ds_read tile it+1 fragments (consumed NEXT iteration)
    if (doNext) {
        const short* kl = ldsk + rOff * (32 * KST);
        const short* vl = ldsv + rOff * (64 * VST);
        #pragma unroll
        for (int h = 0; h < 4; ++h)
            kfn[h] = *(const f16x8*)(kl + m32 * KST + h * 16 + koff);
        #pragma unroll
        for (int t = 0; t < 2; ++t)
            #pragma unroll
            for (int kh = 0; kh < 2; ++kh)
                van[t * 2 + kh] = *(const f16x8*)(vl + (t * 32 + m32) * VST + kh * 16 + koff);
    }

    // (c) compute on current fragments — no memory wait
    #pragma unroll
    for (int qg = 0; qg < 2; ++qg) {
        f32x16 st = __builtin_amdgcn_mfma_f32_32x32x16_f16(kfc[0], qb[qg][0], z16, 0, 0, 0);
        #pragma unroll
        for (int h = 1; h < 4; ++h)
            st = __builtin_amdgcn_mfma_f32_32x32x16_f16(kfc[h], qb[qg][h], st, 0, 0, 0);

        float p[16];
        #pragma unroll
        for (int r = 0; r < 16; ++r) p[r] = EXP2(st[r]);
        float s01 = (p[0]+p[1]) + (p[2]+p[3]);
        float s23 = (p[4]+p[5]) + (p[6]+p[7]);
        float s45 = (p[8]+p[9]) + (p[10]+p[11]);
        float s67 = (p[12]+p[13]) + (p[14]+p[15]);
        pl[qg] += (s01 + s23) + (s45 + s67);

        unsigned int pk[8];
        #pragma unroll
        for (int i = 0; i < 8; ++i)
            pk[i] = __builtin_bit_cast(unsigned int,
                      __builtin_amdgcn_cvt_pkrtz(p[2 * i], p[2 * i + 1]));
        pl32swap(pk[0], pk[2]);
        pl32swap(pk[1], pk[3]);
        pl32swap(pk[4], pk[6]);
        pl32swap(pk[5], pk[7]);

        i32x4 bi0, bi1;
        bi0[0] = (int)pk[0]; bi0[1] = (int)pk[1];
        bi0[2] = (int)pk[2]; bi0[3] = (int)pk[3];
        bi1[0] = (int)pk[4]; bi1[1] = (int)pk[5];
        bi1[2] = (int)pk[6]; bi1[3] = (int)pk[7];
        f16x8 bf0 = __builtin_bit_cast(f16x8, bi0);
        f16x8 bf1 = __builtin_bit_cast(f16x8, bi1);

        #pragma unroll
        for (int t = 0; t < 2; ++t) {
            o[qg][t] = __builtin_amdgcn_mfma_f32_32x32x16_f16(vac[t * 2 + 0], bf0, o[qg][t], 0, 0, 0);
            o[qg][t] = __builtin_amdgcn_mfma_f32_32x32x16_f16(vac[t * 2 + 1], bf1, o[qg][t], 0, 0, 0);
        }
    }

    // (d) ds_write tile it+2 into the free buffer (last read 2 barriers ago)
    if (doStage) {
        *(uint4*)(kdst0 + wOff * (32 * KST)) = kr;
        *(uint4*)(vdst0 + wOff * (64 * VST)) = vr;
    }
    __syncthreads();   // single barrier per iteration

    // rotate buffers: newR = oldW, newW = oldF, newF = oldR
    int t_ = fOff; fOff = rOff; rOff = wOff; wOff = t_;
}

__global__ __launch_bounds__(256, 2)
void flash_kernel(const short* __restrict__ qws, const short* __restrict__ kws,
                  const short* __restrict__ vws, float* __restrict__ out)
{
    __shared__ __align__(16) short ldsk[3 * 32 * KST];   // 13824 B
    __shared__ __align__(16) short ldsv[3 * 64 * VST];   // 15360 B
    __shared__ __align__(16) float olds[4 * 32 * OTS];   // 18432 B (tot 47616)

    const int tid  = threadIdx.x;
    const int wave = tid >> 6;
    const int lane = tid & 63;
    const int m32  = lane & 31;
    const int lh   = lane >> 5;          // lane-half
    const int koff = lh * 8;
    const int bh   = blockIdx.x;                     // XCD = bh % 8
    const int q0   = blockIdx.y * 256 + wave * 64;   // 64 q-rows per wave

    const short* qbase = qws + (size_t)bh * S_ * D_;
    const short* kbase = kws + (size_t)bh * S_ * D_;
    const short* vbase = vws + (size_t)bh * (S_ / 32) * 2048;  // blocked tiles

    // staging addresses (per thread, fixed)
    short* kdst0 = ldsk + (tid >> 3) * KST + (tid & 7) * 8;   // K: 8 thr/row of 64
    short* vdst0 = ldsv + (tid >> 2) * VST + (tid & 3) * 8;   // V: 4 thr/row of 32

    // Q^T B-frags (held): qb[qg][h]: B[d=h*16+lh*8+j][q=m32]
    f16x8 qb[2][4];
    #pragma unroll
    for (int qg = 0; qg < 2; ++qg)
        #pragma unroll
        for (int h = 0; h < 4; ++h)
            qb[qg][h] = *(const f16x8*)(qbase + (q0 + qg * 32 + m32) * D_ + h * 16 + koff);

    f32x16 z16;
    #pragma unroll
    for (int r = 0; r < 16; ++r) z16[r] = 0.f;

    f32x16 o[2][2];      // [qg][d-tile] O^T accumulators
    float  pl[2] = {0.f, 0.f};
    #pragma unroll
    for (int qg = 0; qg < 2; ++qg)
        #pragma unroll
        for (int t = 0; t < 2; ++t)
            o[qg][t] = z16;

    // prologue: stage tiles 0 and 1 into buffers 0 and 1
    {
        uint4 k0 = *(const uint4*)(kbase + (size_t)tid * 8);
        uint4 v0 = *(const uint4*)(vbase + (size_t)tid * 8);
        uint4 k1 = *(const uint4*)(kbase + (size_t)2048 + tid * 8);
        uint4 v1 = *(const uint4*)(vbase + (size_t)2048 + tid * 8);
        *(uint4*)kdst0 = k0;
        *(uint4*)vdst0 = v0;
        *(uint4*)(kdst0 + 32 * KST) = k1;
        *(uint4*)(vdst0 + 64 * VST) = v1;
    }
    __syncthreads();

    // preload tile-0 fragments into register set A
    f16x8 kfA[4], vaA[4], kfB[4], vaB[4];
    #pragma unroll
    for (int h = 0; h < 4; ++h)
        kfA[h] = *(const f16x8*)(ldsk + m32 * KST + h * 16 + koff);
    #pragma unroll
    for (int t = 0; t < 2; ++t)
        #pragma unroll
        for (int kh = 0; kh < 2; ++kh)
            vaA[t * 2 + kh] = *(const f16x8*)(ldsv + (t * 32 + m32) * VST + kh * 16 + koff);

    int rOff = 1, wOff = 2, fOff = 0;   // read-next buf, write buf, free buf

    for (int it = 0; it < 64; it += 2) {
        flash_step(it,     kbase, vbase, ldsk, ldsv, kdst0, vdst0,
                   m32, koff, tid, rOff, wOff, fOff,
                   kfA, vaA, kfB, vaB, qb, z16, o, pl);
        flash_step(it + 1, kbase, vbase, ldsk, ldsv, kdst0, vdst0,
                   m32, koff, tid, rOff, wOff, fOff,
                   kfB, vaB, kfA, vaA, qb, z16, o, pl);
    }

    // epilogue: complete row sums across lane-halves, normalize, transpose
    // O^T -> O one 32-wide d-tile at a time through per-wave LDS (32x36 f32),
    // coalesced f32x4 stores (128B per 8 lanes).
    const int b = bh >> 3, h = bh & 7;
    float* ow = olds + wave * (32 * OTS);
    #pragma unroll
    for (int qg = 0; qg < 2; ++qg) {
        float rs = pl[qg] + __shfl_xor(pl[qg], 32);
        float rl = 1.0f / rs;
        #pragma unroll
        for (int t = 0; t < 2; ++t) {
            const f32x16& ot = o[qg][t];
            #pragma unroll
            for (int g = 0; g < 4; ++g) {
                f32x4 w;
                w[0] = ot[g * 4 + 0] * rl;
                w[1] = ot[g * 4 + 1] * rl;
                w[2] = ot[g * 4 + 2] * rl;
                w[3] = ot[g * 4 + 3] * rl;
                // element (q=m32, dcol=r+8g+4lh) of this 32-wide d-tile
                *(f32x4*)(ow + m32 * OTS + 8 * g + 4 * lh) = w;
            }
            #pragma unroll
            for (int c = 0; c < 4; ++c) {
                const int row = (lane >> 3) + 8 * c;       // q-row within 32-row group
                f32x4 v = *(const f32x4*)(ow + row * OTS + (lane & 7) * 4);
                const int sq = q0 + qg * 32 + row;
                *(f32x4*)(out + ((size_t)(b * S_ + sq)) * DPROJ_
                              + h * 64 + t * 32 + (lane & 7) * 4) = v;
            }
        }
    }
}

// ---------------------------------------------------------------------------
extern "C" void kernel_launch(void* const* d_in, const int* in_sizes, int n_in,
                              void* d_out, int out_size, void* d_ws, size_t ws_size,
                              hipStream_t stream)
{
    const float* query = (const float*)d_in[0];
    const float* key   = (const float*)d_in[1];
    const float* value = (const float*)d_in[2];
    // d_in[3] = mask (int32) -- only its shape feeds the reference; unused.
    const float* Wq = (const float*)d_in[4];
    const float* bq = (const float*)d_in[5];
    const float* Wk = (const float*)d_in[6];
    const float* bk = (const float*)d_in[7];
    const float* Wv = (const float*)d_in[8];
    const float* bv = (const float*)d_in[9];

    float* out = (float*)d_out;
    short* ws  = (short*)d_ws;
    const size_t TSZ = (size_t)BH_ * S_ * D_;
    short* qws = ws;
    short* kws = ws + TSZ;
    short* vws = ws + 2 * TSZ;

    proj_kernel<<<dim3((B_ * S_) / 16, 3), 256, 0, stream>>>(
        query, key, value, Wq, bq, Wk, bk, Wv, bv, qws, kws, vws);
    flash_kernel<<<dim3(BH_, S_ / 256), 256, 0, stream>>>(qws, kws, vws, out);
}

// Round 6
// 184.806 us; speedup vs baseline: 1.5197x; 1.0011x over previous
//
#include <hip/hip_runtime.h>
#include <hip/hip_bf16.h>
#include <math.h>

// Problem constants
#define B_   8
#define H_   8
#define S_   2048
#define D_   64      // head dim
#define BH_  64      // B*H
#define DPROJ_ 512

typedef __attribute__((ext_vector_type(8)))  _Float16 f16x8;
typedef __attribute__((ext_vector_type(4)))  float    f32x4;
typedef __attribute__((ext_vector_type(16))) float    f32x16;
typedef __attribute__((ext_vector_type(4)))  int      i32x4;

static __device__ __forceinline__ short f16bits(float f) {
    return __builtin_bit_cast(short, (_Float16)f);   // v_cvt_f16_f32 (RNE)
}

static __device__ __forceinline__ f16x8 load8_f32_f16(const float* p) {
    const float4 a = ((const float4*)p)[0];
    const float4 b = ((const float4*)p)[1];
    f16x8 r;
    r[0] = (_Float16)a.x; r[1] = (_Float16)a.y; r[2] = (_Float16)a.z; r[3] = (_Float16)a.w;
    r[4] = (_Float16)b.x; r[5] = (_Float16)b.y; r[6] = (_Float16)b.z; r[7] = (_Float16)b.w;
    return r;
}

// exp2: guarantee a single v_exp_f32 (HW computes 2^x)
#if __has_builtin(__builtin_amdgcn_exp2f)
#define EXP2(x) __builtin_amdgcn_exp2f(x)
#else
#define EXP2(x) exp2f(x)
#endif

// permlane32_swap: newA = {A_lo, B_lo}, newB = {A_hi, B_hi}.
static __device__ __forceinline__ void pl32swap(unsigned int& a, unsigned int& b) {
#if __has_builtin(__builtin_amdgcn_permlane32_swap)
    auto r = __builtin_amdgcn_permlane32_swap((int)a, (int)b, false, false);
    a = (unsigned int)r[0];
    b = (unsigned int)r[1];
#else
    const bool lh0 = ((threadIdx.x & 63) < 32);
    unsigned int xa = (unsigned int)__shfl_xor((int)a, 32);
    unsigned int xb = (unsigned int)__shfl_xor((int)b, 32);
    unsigned int na = lh0 ? a : xb;
    unsigned int nb = lh0 ? xa : b;
    a = na; b = nb;
#endif
}

// ---------------------------------------------------------------------------
// R12 WORKSPACE LAYOUTS (fragment-major, so flash loads MFMA operands
// directly from global with fully-coalesced 1KB wave loads — no LDS):
//   q_ws: [bh][s][64] f16 (row layout; Q read once per wave, cost negligible).
//         q pre-scaled by 0.1125*log2(e) for exp2 softmax.
//   k_ws: [bh][T][h][lh][m32][8] f16  (T=s/32, m32=s%32, d=h*16+lh*8+j)
//         -> lane l=(lh*32+m32) of a wave reads frag h at byte l*16: the
//            wave's 64 lanes cover one contiguous 1KB block per h.
//   v_ws: [bh][T][fg][lh][m32][8] f16 (fg=(d>>5)*2+(k8>>1), lh=k8&1,
//         m32=d&31, k=k8*8+j) — identical addressing structure to k_ws.
// Per tile: K = 4 frag-groups x 1KB, V = 4 frag-groups x 1KB.
// ---------------------------------------------------------------------------
#define QKST 520

__global__ __launch_bounds__(256)
void proj_kernel(const float* __restrict__ query, const float* __restrict__ key,
                 const float* __restrict__ value,
                 const float* __restrict__ Wq, const float* __restrict__ bq,
                 const float* __restrict__ Wk, const float* __restrict__ bk,
                 const float* __restrict__ Wv, const float* __restrict__ bv,
                 short* __restrict__ qws, short* __restrict__ kws,
                 short* __restrict__ vws)
{
    __shared__ __align__(16) short shbuf[16384];   // 32 KB, unioned per path

    const int tid  = threadIdx.x;
    const int wave = tid >> 6;
    const int lane = tid & 63;
    const int n    = lane & 15;
    const int quad = lane >> 4;
    const int kind = blockIdx.y;             // 0=q, 1=k, 2=v

    if (kind < 2) {
        short* tile = shbuf;                 // 16 x QKST = 16640 B
        const int r0   = blockIdx.x * 16;
        const int b    = r0 >> 11;
        const int s0   = r0 & 2047;
        // (1-dropout)/num_heads = 0.9/8 = 0.1125, times log2(e) for exp2 softmax
        const float QS = 0.16230319188537014f;

        const float* X    = kind ? key : query;
        const float* W    = kind ? Wk  : Wq;
        const float* bias = kind ? bk  : bq;
        short*       ows  = kind ? kws : qws;

        f16x8 af = load8_f32_f16(X + (r0 + n) * 32 + quad * 8);
        #pragma unroll
        for (int i = 0; i < 8; ++i) {
            const int c0 = wave * 128 + i * 16;
            f16x8 bfr = load8_f32_f16(W + (c0 + n) * 32 + quad * 8);
            f32x4 acc = {0.f, 0.f, 0.f, 0.f};
            acc = __builtin_amdgcn_mfma_f32_16x16x32_f16(af, bfr, acc, 0, 0, 0);
            const int c = c0 + n;
            const float bsf = bias[c];
            #pragma unroll
            for (int r = 0; r < 4; ++r) {
                float v = acc[r] + bsf;
                if (kind == 0) v *= QS;
                tile[(quad * 4 + r) * QKST + c] = f16bits(v);
            }
        }
        __syncthreads();

        #pragma unroll
        for (int k = 0; k < 4; ++k) {
            const int slot = k * 256 + tid;
            const int li   = slot & 7;          // d8 within head = h*2+lh
            const int chunk= slot >> 3;
            const int row  = chunk & 15;
            const int hd   = chunk >> 4;        // head 0..7
            uint4 vv = *(const uint4*)(tile + row * QKST + hd * 64 + li * 8);
            const int bh = b * 8 + hd;
            if (kind == 0) {
                *(uint4*)(ows + ((size_t)bh * S_ + s0 + row) * 64 + li * 8) = vv;
            } else {
                const int s = s0 + row;
                // k frag layout: bh*S*64 + T*2048 + li*256 + m32*8
                *(uint4*)(ows + (size_t)bh * (S_ * 64)
                              + (size_t)(s >> 5) * 2048 + li * 256 + (s & 31) * 8) = vv;
            }
        }
    } else {
        if (blockIdx.x >= 256) return;       // v path needs only 256 blocks
        short* vtile = shbuf;                // 2*256*32 shorts = 32768 B
        const int r0   = blockIdx.x * 64;
        const int b    = r0 >> 11;
        const int s0   = r0 & 2047;
        const int sub  = wave >> 1;
        const int sh   = (wave & 1) * 16;

        #pragma unroll
        for (int half = 0; half < 2; ++half) {
            const int cbh = half * 256;
            f16x8 bfr = load8_f32_f16(value + (r0 + sub * 32 + sh + n) * 32 + quad * 8);
            #pragma unroll
            for (int i = 0; i < 16; ++i) {
                const int c0 = cbh + i * 16;
                f16x8 af = load8_f32_f16(Wv + (c0 + n) * 32 + quad * 8);
                f32x4 acc = {0.f, 0.f, 0.f, 0.f};
                acc = __builtin_amdgcn_mfma_f32_16x16x32_f16(af, bfr, acc, 0, 0, 0);
                #pragma unroll
                for (int r = 0; r < 4; ++r) {
                    const int dc = c0 + quad * 4 + r;
                    float v = acc[r] + bv[dc];
                    vtile[(sub * 256 + (dc - cbh)) * 32 + sh + n] = f16bits(v);
                }
            }
            __syncthreads();

            #pragma unroll
            for (int k = 0; k < 8; ++k) {
                const int slot = k * 256 + tid;
                const int li   = slot & 3;          // k8 within tile (0..3)
                const int cl   = (slot >> 2) & 255;
                const int sb   = slot >> 10;
                const int c    = cbh + cl;
                const int bh   = b * 8 + (c >> 6);
                const int d    = c & 63;
                const int stile= (s0 >> 5) + sb;
                uint4 vv = *(const uint4*)(vtile + (sb * 256 + cl) * 32 + li * 8);
                // v frag layout: bh*S*64 + T*2048 + ((d>>5)*4+(li>>1)*2+(li&1))*256 + m32*8
                *(uint4*)(vws + (size_t)bh * (S_ * 64)
                              + (size_t)stile * 2048
                              + ((d >> 5) * 4 + (li >> 1) * 2 + (li & 1)) * 256
                              + (d & 31) * 8) = vv;
            }
            if (half == 0) __syncthreads();  // reuse vtile for second half
        }
    }
}

// ---------------------------------------------------------------------------
// Kernel 2: flash attention. R12: PURE-REGISTER STREAMING (no LDS in loop).
// Rounds 2/4/5 all pinned at 81 us across three schedules -> throughput
// wall, not latency. Per CU round: LDS pipe ~960 cyc (8 waves x 10 b128
// ops) and VALU ~888 cyc were JOINTLY saturated. Fix: workspace now stores
// K/V in fragment-major layout, so each wave loads its MFMA operands
// directly from global: 8 x fully-contiguous 1KB global_load_dwordx4 per
// 32-k tile (lane l reads byte l*16 of each 1KB frag-group). The original
// session's "32-cacheline gather" failure is avoided because layout now
// matches lane order exactly. Deleted: all staging, all ds_read/ds_write,
// ALL barriers (epilogue LDS is per-wave, no sync). Re-read amplification
// (4 waves x same tile) is served by per-XCD L2 (~2.1 of 4.3 TB/s;
// XCD-aware grid keeps each bh's 512KB resident). Latency hidden by A/B
// register ping-pong prefetch one tile ahead (proven in R11).
// Retained: 4 waves x 64 q-rows, grid (BH, S/256), exp2 softmax,
// permlane32_swap packing.
// ---------------------------------------------------------------------------
#define OTS 36   // epilogue LDS row stride (f32) for one 32-wide d-tile

static __device__ __forceinline__ void flash_compute(
    const f16x8 (&kf)[4], const f16x8 (&va)[4],
    const f16x8 (&qb)[2][4], const f32x16& z16,
    f32x16 (&o)[2][2], float (&pl)[2])
{
    #pragma unroll
    for (int qg = 0; qg < 2; ++qg) {
        f32x16 st = __builtin_amdgcn_mfma_f32_32x32x16_f16(kf[0], qb[qg][0], z16, 0, 0, 0);
        #pragma unroll
        for (int h = 1; h < 4; ++h)
            st = __builtin_amdgcn_mfma_f32_32x32x16_f16(kf[h], qb[qg][h], st, 0, 0, 0);

        float p[16];
        #pragma unroll
        for (int r = 0; r < 16; ++r) p[r] = EXP2(st[r]);
        float s01 = (p[0]+p[1]) + (p[2]+p[3]);
        float s23 = (p[4]+p[5]) + (p[6]+p[7]);
        float s45 = (p[8]+p[9]) + (p[10]+p[11]);
        float s67 = (p[12]+p[13]) + (p[14]+p[15]);
        pl[qg] += (s01 + s23) + (s45 + s67);

        unsigned int pk[8];
        #pragma unroll
        for (int i = 0; i < 8; ++i)
            pk[i] = __builtin_bit_cast(unsigned int,
                      __builtin_amdgcn_cvt_pkrtz(p[2 * i], p[2 * i + 1]));
        pl32swap(pk[0], pk[2]);
        pl32swap(pk[1], pk[3]);
        pl32swap(pk[4], pk[6]);
        pl32swap(pk[5], pk[7]);

        i32x4 bi0, bi1;
        bi0[0] = (int)pk[0]; bi0[1] = (int)pk[1];
        bi0[2] = (int)pk[2]; bi0[3] = (int)pk[3];
        bi1[0] = (int)pk[4]; bi1[1] = (int)pk[5];
        bi1[2] = (int)pk[6]; bi1[3] = (int)pk[7];
        f16x8 bf0 = __builtin_bit_cast(f16x8, bi0);
        f16x8 bf1 = __builtin_bit_cast(f16x8, bi1);

        #pragma unroll
        for (int t = 0; t < 2; ++t) {
            o[qg][t] = __builtin_amdgcn_mfma_f32_32x32x16_f16(va[t * 2 + 0], bf0, o[qg][t], 0, 0, 0);
            o[qg][t] = __builtin_amdgcn_mfma_f32_32x32x16_f16(va[t * 2 + 1], bf1, o[qg][t], 0, 0, 0);
        }
    }
}

__global__ __launch_bounds__(256, 2)
void flash_kernel(const short* __restrict__ qws, const short* __restrict__ kws,
                  const short* __restrict__ vws, float* __restrict__ out)
{
    __shared__ __align__(16) float olds[4 * 32 * OTS];   // 18432 B (epilogue only)

    const int tid  = threadIdx.x;
    const int wave = tid >> 6;
    const int lane = tid & 63;
    const int m32  = lane & 31;
    const int lh   = lane >> 5;          // lane-half
    const int koff = lh * 8;
    const int bh   = blockIdx.x;                     // XCD = bh % 8
    const int q0   = blockIdx.y * 256 + wave * 64;   // 64 q-rows per wave

    const short* qbase = qws + (size_t)bh * S_ * D_;
    const short* kfb   = kws + (size_t)bh * (S_ * 64);   // frag-major tiles
    const short* vfb   = vws + (size_t)bh * (S_ * 64);
    const int loff = lh * 256 + m32 * 8;                 // lane part of frag addr

    // Q^T B-frags (held): qb[qg][h]: B[d=h*16+lh*8+j][q=m32]
    f16x8 qb[2][4];
    #pragma unroll
    for (int qg = 0; qg < 2; ++qg)
        #pragma unroll
        for (int h = 0; h < 4; ++h)
            qb[qg][h] = *(const f16x8*)(qbase + (q0 + qg * 32 + m32) * D_ + h * 16 + koff);

    f32x16 z16;
    #pragma unroll
    for (int r = 0; r < 16; ++r) z16[r] = 0.f;

    f32x16 o[2][2];      // [qg][d-tile] O^T accumulators
    float  pl[2] = {0.f, 0.f};
    #pragma unroll
    for (int qg = 0; qg < 2; ++qg)
        #pragma unroll
        for (int t = 0; t < 2; ++t)
            o[qg][t] = z16;

    // frag loads: 8 contiguous 1KB wave-loads per tile, direct from global
    #define LOADFRAGS(T, kf, va) do {                                        \
        const short* kp_ = kfb + (size_t)(T) * 2048 + loff;                  \
        const short* vp_ = vfb + (size_t)(T) * 2048 + loff;                  \
        kf[0] = *(const f16x8*)(kp_);                                        \
        kf[1] = *(const f16x8*)(kp_ + 512);                                  \
        kf[2] = *(const f16x8*)(kp_ + 1024);                                 \
        kf[3] = *(const f16x8*)(kp_ + 1536);                                 \
        va[0] = *(const f16x8*)(vp_);                                        \
        va[1] = *(const f16x8*)(vp_ + 512);                                  \
        va[2] = *(const f16x8*)(vp_ + 1024);                                 \
        va[3] = *(const f16x8*)(vp_ + 1536);                                 \
    } while (0)

    f16x8 kfA[4], vaA[4], kfB[4], vaB[4];
    LOADFRAGS(0, kfA, vaA);

    for (int it = 0; it < 64; it += 2) {
        LOADFRAGS(it + 1, kfB, vaB);             // it+1 <= 63 always
        flash_compute(kfA, vaA, qb, z16, o, pl);
        if (it + 2 < 64)
            LOADFRAGS(it + 2, kfA, vaA);
        flash_compute(kfB, vaB, qb, z16, o, pl);
    }
    #undef LOADFRAGS

    // epilogue: complete row sums across lane-halves, normalize, transpose
    // O^T -> O one 32-wide d-tile at a time through per-wave LDS (32x36 f32,
    // per-wave region — no cross-wave hazard, no barrier), coalesced stores.
    const int b = bh >> 3, h = bh & 7;
    float* ow = olds + wave * (32 * OTS);
    #pragma unroll
    for (int qg = 0; qg < 2; ++qg) {
        float rs = pl[qg] + __shfl_xor(pl[qg], 32);
        float rl = 1.0f / rs;
        #pragma unroll
        for (int t = 0; t < 2; ++t) {
            const f32x16& ot = o[qg][t];
            #pragma unroll
            for (int g = 0; g < 4; ++g) {
                f32x4 w;
                w[0] = ot[g * 4 + 0] * rl;
                w[1] = ot[g * 4 + 1] * rl;
                w[2] = ot[g * 4 + 2] * rl;
                w[3] = ot[g * 4 + 3] * rl;
                // element (q=m32, dcol=r+8g+4lh) of this 32-wide d-tile
                *(f32x4*)(ow + m32 * OTS + 8 * g + 4 * lh) = w;
            }
            #pragma unroll
            for (int c = 0; c < 4; ++c) {
                const int row = (lane >> 3) + 8 * c;       // q-row within 32-row group
                f32x4 v = *(const f32x4*)(ow + row * OTS + (lane & 7) * 4);
                const int sq = q0 + qg * 32 + row;
                *(f32x4*)(out + ((size_t)(b * S_ + sq)) * DPROJ_
                              + h * 64 + t * 32 + (lane & 7) * 4) = v;
            }
        }
    }
}

// ---------------------------------------------------------------------------
extern "C" void kernel_launch(void* const* d_in, const int* in_sizes, int n_in,
                              void* d_out, int out_size, void* d_ws, size_t ws_size,
                              hipStream_t stream)
{
    const float* query = (const float*)d_in[0];
    const float* key   = (const float*)d_in[1];
    const float* value = (const float*)d_in[2];
    // d_in[3] = mask (int32) -- only its shape feeds the reference; unused.
    const float* Wq = (const float*)d_in[4];
    const float* bq = (const float*)d_in[5];
    const float* Wk = (const float*)d_in[6];
    const float* bk = (const float*)d_in[7];
    const float* Wv = (const float*)d_in[8];
    const float* bv = (const float*)d_in[9];

    float* out = (float*)d_out;
    short* ws  = (short*)d_ws;
    const size_t TSZ = (size_t)BH_ * S_ * D_;
    short* qws = ws;
    short* kws = ws + TSZ;
    short* vws = ws + 2 * TSZ;

    proj_kernel<<<dim3((B_ * S_) / 16, 3), 256, 0, stream>>>(
        query, key, value, Wq, bq, Wk, bk, Wv, bv, qws, kws, vws);
    flash_kernel<<<dim3(BH_, S_ / 256), 256, 0, stream>>>(qws, kws, vws, out);
}